// Round 3
// baseline (5197.345 us; speedup 1.0000x reference)
//
#include <hip/hip_runtime.h>

// HMM forward (CgpHmmLayer): B=64, T=4096, S=305.
// Kernel 1 (prep_A): row-softmax the transition kernel into d_ws as a padded
//   320x320 f32 matrix (rows/cols >= 305 are zero).
// Kernel 2 (hmm_fwd): one workgroup per batch element (64 WGs, 512 thr = 8 waves).
//   Wave w owns rows [40w, 40w+40); lane l owns cols {l, l+64, ..., l+256}.
//   areg[40][5] = 200 VGPRs/thread, loaded from d_ws with constant indices
//   (trivial init -> no spill; 512-thr block caps VGPR at 256).
//   Per step: 40 readlane broadcasts + 200 FMA, partial column sums through a
//   ping-pong LDS buffer, ONE barrier/step; each wave gathers exactly its own
//   40 columns (= its rows next step) so alpha stays in registers.
//   Normalize every 8 steps; log(s) telescopes exactly. Init-softmax normalizer
//   folded into a final -log(Z_I).

constexpr int NS  = 305;   // states
constexpr int NSP = 320;   // padded states
constexpr int NT  = 4096;  // time steps
constexpr int NW  = 8;     // waves per block
constexpr int RPW = 40;    // rows per wave (NSP/NW)
constexpr int CPT = 5;     // cols per thread (NSP/64)
constexpr int NORM_MASK = 7; // normalize every 8 steps

__global__ __launch_bounds__(64)
void prep_A(const float* __restrict__ transk, float* __restrict__ wsA)
{
    const int r = blockIdx.x;      // padded row 0..319
    const int l = threadIdx.x;     // lane 0..63
    if (r < NS) {
        float e[CPT];
        float part = 0.f;
        #pragma unroll
        for (int k = 0; k < CPT; ++k) {
            const int c = l + 64 * k;
            e[k] = (c < NS) ? __expf(transk[r * NS + c]) : 0.f;
            part += e[k];
        }
        #pragma unroll
        for (int off = 32; off; off >>= 1) part += __shfl_xor(part, off, 64);
        const float inv = 1.f / part;
        #pragma unroll
        for (int k = 0; k < CPT; ++k)
            wsA[r * NSP + l + 64 * k] = e[k] * inv;
    } else {
        #pragma unroll
        for (int k = 0; k < CPT; ++k)
            wsA[r * NSP + l + 64 * k] = 0.f;
    }
}

__global__ __launch_bounds__(512)
void hmm_fwd(const float* __restrict__ inputs,
             const float* __restrict__ initk,
             const float* __restrict__ emisk,
             const float* __restrict__ wsA,
             float* __restrict__ out)
{
    __shared__ float sBm[4 * NSP];          // emission probs, [obs][state], padded 0
    __shared__ float sI[NSP];               // exp(init_kernel), padded 0
    __shared__ unsigned char sObs[NT];      // observation indices for this batch
    __shared__ float sPart[2][NW * NSP];    // ping-pong partial column sums
    __shared__ float sN[16];                // small reduce buffer (ping-pong 8+8)

    const int tid = threadIdx.x;
    const int w   = tid >> 6;   // wave id 0..7
    const int l   = tid & 63;   // lane id
    const int b   = blockIdx.x; // batch element

    // ---- zero-init padded LDS regions ----
    for (int i = tid; i < 4 * NSP; i += 512) sBm[i] = 0.f;
    for (int i = tid; i < NSP;     i += 512) sI[i]  = 0.f;
    __syncthreads();

    // ---- decode one-hot observations for this batch (coalesced float4) ----
    const float4* oh = (const float4*)(inputs + (size_t)b * NT * 4);
    #pragma unroll
    for (int i = 0; i < NT / 512; ++i) {
        int t = tid + i * 512;
        float4 v = oh[t];
        sObs[t] = (unsigned char)(int)(v.y + 2.f * v.z + 3.f * v.w + 0.5f);
    }

    // ---- emission softmax over 4 (per state) ----
    if (tid < NS) {
        float4 ek = ((const float4*)emisk)[tid];
        float e0 = __expf(ek.x), e1 = __expf(ek.y), e2 = __expf(ek.z), e3 = __expf(ek.w);
        float inv = 1.f / (e0 + e1 + e2 + e3);
        sBm[0 * NSP + tid] = e0 * inv;
        sBm[1 * NSP + tid] = e1 * inv;
        sBm[2 * NSP + tid] = e2 * inv;
        sBm[3 * NSP + tid] = e3 * inv;
    }

    // ---- init vector: exp only; normalizer Z_I folded at the end ----
    if (tid < NS) sI[tid] = __expf(initk[tid]);
    __syncthreads();

    // ---- log(Z_I): reduce sI over all states ----
    float v0 = (tid < NSP) ? sI[tid] : 0.f;
    #pragma unroll
    for (int off = 32; off; off >>= 1) v0 += __shfl_xor(v0, off, 64);
    if (l == 0) sN[w] = v0;
    __syncthreads();
    float z = 0.f;
    #pragma unroll
    for (int i = 0; i < 8; ++i) z += sN[i];
    const float logZI = __logf(z);
    __syncthreads();   // sN safe for reuse

    // ---- load register-cached transition slice (trivial init: pure loads) ----
    float areg[RPW][CPT];
    {
        const float* wa = wsA + (size_t)(w * RPW) * NSP + l;
        #pragma unroll
        for (int j = 0; j < RPW; ++j) {
            #pragma unroll
            for (int k = 0; k < CPT; ++k)
                areg[j][k] = wa[j * NSP + 64 * k];
        }
    }

    // ---- t = 0: alpha0 (unnormalized) = exp(init) * e0, kept in registers ----
    float va = 0.f;
    {
        int o0 = sObs[0];
        int col = w * RPW + l;
        if (l < RPW) va = sI[col] * sBm[o0 * NSP + col];
    }
    float ll = 0.f;

    // ---- main scan ----
    for (int t = 1; t < NT; ++t) {
        // prefetch emission for the columns this wave will gather
        const int o = sObs[t];
        const float ecol = (l < RPW) ? sBm[o * NSP + w * RPW + l] : 0.f;

        // matvec: acc[c] += alpha[row] * A[row][c], alpha broadcast via readlane
        float acc[CPT] = {0.f, 0.f, 0.f, 0.f, 0.f};
        #pragma unroll
        for (int j = 0; j < RPW; ++j) {
            float sa = __uint_as_float(
                __builtin_amdgcn_readlane(__float_as_uint(va), j));
            #pragma unroll
            for (int k = 0; k < CPT; ++k)
                acc[k] = fmaf(sa, areg[j][k], acc[k]);
        }

        // write partial column sums (ping-pong buffer -> single barrier per step)
        float* pb = sPart[t & 1];
        #pragma unroll
        for (int k = 0; k < CPT; ++k)
            pb[w * NSP + l + 64 * k] = acc[k];
        __syncthreads();

        // gather: each wave assembles the 40 columns that are its rows next step
        if (l < RPW) {
            const int col = w * RPW + l;
            float s8 = 0.f;
            #pragma unroll
            for (int ww = 0; ww < NW; ++ww) s8 += pb[ww * NSP + col];
            va = s8 * ecol;
        } else {
            va = 0.f;
        }

        // periodic normalization + log-likelihood accumulation
        if ((t & NORM_MASK) == NORM_MASK) {
            float v = (l < RPW) ? va : 0.f;
            #pragma unroll
            for (int off = 32; off; off >>= 1) v += __shfl_xor(v, off, 64);
            const int nb = (t >> 3) & 1;
            if (l == 0) sN[nb * 8 + w] = v;
            __syncthreads();
            float tot = 0.f;
            #pragma unroll
            for (int i = 0; i < 8; ++i) tot += sN[nb * 8 + i];
            ll += __logf(tot);
            va *= 1.f / tot;
        }
    }

    if (tid == 0) out[b] = ll - logZI;
}

extern "C" void kernel_launch(void* const* d_in, const int* in_sizes, int n_in,
                              void* d_out, int out_size, void* d_ws, size_t ws_size,
                              hipStream_t stream) {
    const float* inputs = (const float*)d_in[0];
    const float* initk  = (const float*)d_in[1];
    const float* transk = (const float*)d_in[2];
    const float* emisk  = (const float*)d_in[3];
    float* wsA = (float*)d_ws;   // 320*320*4 = 409600 bytes

    hipLaunchKernelGGL(prep_A, dim3(NSP), dim3(64), 0, stream, transk, wsA);
    hipLaunchKernelGGL(hmm_fwd, dim3(64), dim3(512), 0, stream,
                       inputs, initk, emisk, wsA, (float*)d_out);
}

// Round 4
// 4754.723 us; speedup vs baseline: 1.0931x; 1.0931x over previous
//
#include <hip/hip_runtime.h>

// HMM forward (CgpHmmLayer): B=64, T=4096, S=305.
// prep_A: row-softmax transition kernel -> d_ws as padded 320x320 f32 (pad rows/cols zero).
// hmm_fwd: one WG per batch element (64 WGs, 512 thr = 8 waves, 2 waves/SIMD).
//   Wave w owns rows [40w,40w+40); lane l owns cols {l, l+64, ..., l+256}.
//   A-slice held in 40 NAMED ext_vector(5) floats (a0..a39) -> pure SSA, no alloca,
//   cannot be demoted to scratch (rounds 1/3: float areg[40][5] stayed an alloca ->
//   400KB/block scratch re-streamed every step, FETCH 3.7GB, 5.2ms).
//   launch_bounds(512,2) budgets 256 VGPR (200 A + ~25 working).
//   Per step: 40 readlane broadcasts + 200 fmac, partial column sums via ping-pong
//   LDS buffer, ONE barrier/step; each wave gathers exactly its own 40 columns.
//   Normalize every 8 steps; log(s) telescopes exactly; init normalizer -> -log(Z_I).

constexpr int NS  = 305;
constexpr int NSP = 320;
constexpr int NT  = 4096;
constexpr int NW  = 8;
constexpr int RPW = 40;   // rows per wave
constexpr int CPT = 5;    // cols per thread
constexpr int NORM_MASK = 7;

typedef float v5 __attribute__((ext_vector_type(5)));

#define FORTY(X) X(0) X(1) X(2) X(3) X(4) X(5) X(6) X(7) X(8) X(9) \
  X(10) X(11) X(12) X(13) X(14) X(15) X(16) X(17) X(18) X(19) \
  X(20) X(21) X(22) X(23) X(24) X(25) X(26) X(27) X(28) X(29) \
  X(30) X(31) X(32) X(33) X(34) X(35) X(36) X(37) X(38) X(39)

__global__ __launch_bounds__(64)
void prep_A(const float* __restrict__ transk, float* __restrict__ wsA)
{
    const int r = blockIdx.x;      // padded row 0..319
    const int l = threadIdx.x;     // lane 0..63
    if (r < NS) {
        float e[CPT];
        float part = 0.f;
        #pragma unroll
        for (int k = 0; k < CPT; ++k) {
            const int c = l + 64 * k;
            e[k] = (c < NS) ? __expf(transk[r * NS + c]) : 0.f;
            part += e[k];
        }
        #pragma unroll
        for (int off = 32; off; off >>= 1) part += __shfl_xor(part, off, 64);
        const float inv = 1.f / part;
        #pragma unroll
        for (int k = 0; k < CPT; ++k)
            wsA[r * NSP + l + 64 * k] = e[k] * inv;
    } else {
        #pragma unroll
        for (int k = 0; k < CPT; ++k)
            wsA[r * NSP + l + 64 * k] = 0.f;
    }
}

__global__ __launch_bounds__(512, 2)
void hmm_fwd(const float* __restrict__ inputs,
             const float* __restrict__ initk,
             const float* __restrict__ emisk,
             const float* __restrict__ wsA,
             float* __restrict__ out)
{
    __shared__ float sBm[4 * NSP];
    __shared__ float sI[NSP];
    __shared__ unsigned char sObs[NT];
    __shared__ float sPart[2][NW * NSP];
    __shared__ float sN[16];

    const int tid = threadIdx.x;
    const int w   = tid >> 6;
    const int l   = tid & 63;
    const int b   = blockIdx.x;

    for (int i = tid; i < 4 * NSP; i += 512) sBm[i] = 0.f;
    for (int i = tid; i < NSP;     i += 512) sI[i]  = 0.f;
    __syncthreads();

    // decode one-hot observations (coalesced float4)
    const float4* oh = (const float4*)(inputs + (size_t)b * NT * 4);
    #pragma unroll
    for (int i = 0; i < NT / 512; ++i) {
        int t = tid + i * 512;
        float4 v = oh[t];
        sObs[t] = (unsigned char)(int)(v.y + 2.f * v.z + 3.f * v.w + 0.5f);
    }

    // emission softmax over 4
    if (tid < NS) {
        float4 ek = ((const float4*)emisk)[tid];
        float e0 = __expf(ek.x), e1 = __expf(ek.y), e2 = __expf(ek.z), e3 = __expf(ek.w);
        float inv = 1.f / (e0 + e1 + e2 + e3);
        sBm[0 * NSP + tid] = e0 * inv;
        sBm[1 * NSP + tid] = e1 * inv;
        sBm[2 * NSP + tid] = e2 * inv;
        sBm[3 * NSP + tid] = e3 * inv;
    }

    // init vector: exp only; normalizer folded at the end
    if (tid < NS) sI[tid] = __expf(initk[tid]);
    __syncthreads();

    // log(Z_I)
    float v0 = (tid < NSP) ? sI[tid] : 0.f;
    #pragma unroll
    for (int off = 32; off; off >>= 1) v0 += __shfl_xor(v0, off, 64);
    if (l == 0) sN[w] = v0;
    __syncthreads();
    float z = 0.f;
    #pragma unroll
    for (int i = 0; i < 8; ++i) z += sN[i];
    const float logZI = __logf(z);
    __syncthreads();   // sN safe for reuse

    // ---- A-slice in 40 named SSA vectors (no alloca -> guaranteed VGPRs) ----
    const float* wa = wsA + (size_t)(w * RPW) * NSP + l;
#define DECLA(J) v5 a##J;
    FORTY(DECLA)
#undef DECLA
#define LOADA(J) \
    a##J[0] = wa[J * NSP];          \
    a##J[1] = wa[J * NSP + 64];     \
    a##J[2] = wa[J * NSP + 128];    \
    a##J[3] = wa[J * NSP + 192];    \
    a##J[4] = wa[J * NSP + 256];
    FORTY(LOADA)
#undef LOADA
    // pin the loads before the loop: compiler may not re-sink them past this
    asm volatile("" ::: "memory");

    // t = 0
    float va = 0.f;
    {
        int o0 = sObs[0];
        int col = w * RPW + l;
        if (l < RPW) va = sI[col] * sBm[o0 * NSP + col];
    }
    float ll = 0.f;

    // ---- main scan ----
    for (int t = 1; t < NT; ++t) {
        const int o = sObs[t];
        const float ecol = (l < RPW) ? sBm[o * NSP + w * RPW + l] : 0.f;

        v5 acc = {0.f, 0.f, 0.f, 0.f, 0.f};
#define FMAA(J) { \
        float sa = __uint_as_float(__builtin_amdgcn_readlane(__float_as_uint(va), J)); \
        acc += sa * a##J; }
        FORTY(FMAA)
#undef FMAA

        float* pb = sPart[t & 1];
        pb[w * NSP + l      ] = acc[0];
        pb[w * NSP + l +  64] = acc[1];
        pb[w * NSP + l + 128] = acc[2];
        pb[w * NSP + l + 192] = acc[3];
        pb[w * NSP + l + 256] = acc[4];
        __syncthreads();

        if (l < RPW) {
            const int col = w * RPW + l;
            float s8 = 0.f;
            #pragma unroll
            for (int ww = 0; ww < NW; ++ww) s8 += pb[ww * NSP + col];
            va = s8 * ecol;
        } else {
            va = 0.f;
        }

        if ((t & NORM_MASK) == NORM_MASK) {
            float v = (l < RPW) ? va : 0.f;
            #pragma unroll
            for (int off = 32; off; off >>= 1) v += __shfl_xor(v, off, 64);
            const int nb = (t >> 3) & 1;
            if (l == 0) sN[nb * 8 + w] = v;
            __syncthreads();
            float tot = 0.f;
            #pragma unroll
            for (int i = 0; i < 8; ++i) tot += sN[nb * 8 + i];
            ll += __logf(tot);
            va *= 1.f / tot;
        }
    }

    if (tid == 0) out[b] = ll - logZI;
}

extern "C" void kernel_launch(void* const* d_in, const int* in_sizes, int n_in,
                              void* d_out, int out_size, void* d_ws, size_t ws_size,
                              hipStream_t stream) {
    const float* inputs = (const float*)d_in[0];
    const float* initk  = (const float*)d_in[1];
    const float* transk = (const float*)d_in[2];
    const float* emisk  = (const float*)d_in[3];
    float* wsA = (float*)d_ws;   // 320*320*4 = 409600 bytes

    hipLaunchKernelGGL(prep_A, dim3(NSP), dim3(64), 0, stream, transk, wsA);
    hipLaunchKernelGGL(hmm_fwd, dim3(64), dim3(512), 0, stream,
                       inputs, initk, emisk, wsA, (float*)d_out);
}